// Round 1
// baseline (791.448 us; speedup 1.0000x reference)
//
#include <hip/hip_runtime.h>

#define KVOX 12000
#define TPTS 35
#define FIN  7
#define DD   10
#define HH   400
#define WW   352
#define CO   128
#define EPSBN 1e-3f
#define NCELL (DD * HH * WW)              // 1,408,000 cells
#define TOTALF4 ((size_t)NCELL * 32)      // 45,056,000 float4s = 720.9 MB
#define FILLB 2048                        // fill grid: 8 blocks/CU
#define CB    3000                        // compute grid: 4 waves = 4 voxels/block

static_assert(CB * 4 == KVOX, "grid covers voxels exactly");

// ---- kernel 1: zero-fill the output, exactly NCELL*128 floats = 720.9 MB ----
// Pure HBM-write-bound. fillBufferAligned measured ~6.3 TB/s on this chip;
// a grid-stride float4 fill matches that. NOTE: do NOT use hipMemsetAsync
// with out_size*sizeof(float) — out_size is in BYTES (rocprof showed the old
// fallback memset writing exactly 4x the output = 2.88 GB, 458 us).
__global__ __launch_bounds__(256) void fill_out(float4* __restrict__ o4)
{
    const float4 z = make_float4(0.f, 0.f, 0.f, 0.f);
    const size_t stride = (size_t)FILLB * 256;
    for (size_t i = (size_t)blockIdx.x * 256 + threadIdx.x; i < TOTALF4; i += stride)
        o4[i] = z;
}

// ---- kernel 2: VFE compute (wave per voxel) + direct atomic scatter ----
// Math identical to the harness-verified vfe_scatter_atomic (passed=true),
// restructured 4 voxels/block. No workspace: voxelwise row goes straight to
// out via atomicAdd (tf.scatter_nd duplicate semantics). ~12k voxels of
// duplicates over 1.4M cells -> negligible contention.
__global__ __launch_bounds__(256) void vfe_scatter(
    const float* __restrict__ feat,
    const float* __restrict__ w1, const float* __restrict__ b1,
    const float* __restrict__ g1, const float* __restrict__ be1,
    const float* __restrict__ m1, const float* __restrict__ v1,
    const float* __restrict__ w2, const float* __restrict__ b2,
    const float* __restrict__ g2, const float* __restrict__ be2,
    const float* __restrict__ m2, const float* __restrict__ v2,
    const int* __restrict__ coord,
    float* __restrict__ out)
{
    const int tid  = threadIdx.x;
    const int wv   = tid >> 6;        // wave in block: 0..3
    const int lane = tid & 63;
    const int k    = blockIdx.x * 4 + wv;

    __shared__ __align__(16) float sxp[4][TPTS][8];    // padded point features
    __shared__ __align__(16) float spwm[4][TPTS][16];  // masked stage-1 pointwise
    __shared__ __align__(16) float sagg[4][16];        // stage-1 aggregate (unmasked)

    const float* fk = feat + (size_t)k * (TPTS * FIN);

    // stage features into LDS, padded rows of 8 (row pad -> b128 reads later)
    for (int i = lane; i < TPTS * FIN; i += 64)
        sxp[wv][i / FIN][i % FIN] = fk[i];
    if (lane < TPTS) sxp[wv][lane][FIN] = 0.0f;

    // mask per point straight from global (L1/L2-hot)
    bool pred = false;
    if (lane < TPTS) {
        const float* row = fk + lane * FIN;
        float mx = row[0];
        #pragma unroll
        for (int f = 1; f < FIN; ++f) mx = fmaxf(mx, row[f]);
        pred = (mx != 0.0f);
    }
    const unsigned long long bal = __ballot(pred);   // bit t = mask[t] (wave-uniform)
    const int nvalid = __popcll(bal);
    __syncthreads();

    // stage 1: dense(7->16)+relu+BN on lanes u<16; agg over ALL t; masked store
    if (lane < 16) {
        const int u = lane;
        float w1c[8];
        #pragma unroll
        for (int f = 0; f < FIN; ++f) w1c[f] = w1[f * 16 + u];
        w1c[FIN] = 0.0f;
        const float b     = b1[u];
        const float scale = g1[u] * rsqrtf(v1[u] + EPSBN);
        const float shift = be1[u] - m1[u] * scale;

        float agg = -INFINITY;
        float pw[TPTS];
        #pragma unroll
        for (int t = 0; t < TPTS; ++t) {
            const float4 xa = *(const float4*)&sxp[wv][t][0];  // broadcast b128
            const float4 xb = *(const float4*)&sxp[wv][t][4];
            float d = b;
            d = fmaf(xa.x, w1c[0], d); d = fmaf(xa.y, w1c[1], d);
            d = fmaf(xa.z, w1c[2], d); d = fmaf(xa.w, w1c[3], d);
            d = fmaf(xb.x, w1c[4], d); d = fmaf(xb.y, w1c[5], d);
            d = fmaf(xb.z, w1c[6], d); d = fmaf(xb.w, w1c[7], d);
            d = fmaxf(d, 0.0f);
            const float p = fmaf(d, scale, shift);
            agg = fmaxf(agg, p);
            pw[t] = p;
        }
        sagg[wv][u] = agg;
        #pragma unroll
        for (int t = 0; t < TPTS; ++t) {
            const float mk = ((bal >> t) & 1ULL) ? 1.0f : 0.0f;
            spwm[wv][t][u] = pw[t] * mk;     // banks (t*16+u)%32: conflict-free
        }
    }
    __syncthreads();

    // stage 2: dense(32->64)+relu+BN, channel v per lane, agg-term factorized
    {
        const int v = lane;
        float w2c[32];
        #pragma unroll
        for (int u = 0; u < 32; ++u) w2c[u] = w2[u * 64 + v];
        const float b     = b2[v];
        const float scale = g2[v] * rsqrtf(v2[v] + EPSBN);
        const float shift = be2[v] - m2[v] * scale;

        // aggdot = sum_u agg[u] * w2c[16+u]  (t-independent)
        float aggdot = 0.0f;
        {
            const float4* ar = (const float4*)&sagg[wv][0];
            #pragma unroll
            for (int q = 0; q < 4; ++q) {
                const float4 a = ar[q];
                aggdot = fmaf(a.x, w2c[16 + 4 * q + 0], aggdot);
                aggdot = fmaf(a.y, w2c[16 + 4 * q + 1], aggdot);
                aggdot = fmaf(a.z, w2c[16 + 4 * q + 2], aggdot);
                aggdot = fmaf(a.w, w2c[16 + 4 * q + 3], aggdot);
            }
        }

        float aggAll = -INFINITY;
        float voxA   = -INFINITY;
        #pragma unroll 7
        for (int t = 0; t < TPTS; ++t) {
            const float mk = ((bal >> t) & 1ULL) ? 1.0f : 0.0f;
            const float4* xr = (const float4*)&spwm[wv][t][0];
            float d = fmaf(mk, aggdot, b);
            #pragma unroll
            for (int q = 0; q < 4; ++q) {
                const float4 xv = xr[q];          // broadcast b128
                d = fmaf(xv.x, w2c[4 * q + 0], d);
                d = fmaf(xv.y, w2c[4 * q + 1], d);
                d = fmaf(xv.z, w2c[4 * q + 2], d);
                d = fmaf(xv.w, w2c[4 * q + 3], d);
            }
            d = fmaxf(d, 0.0f);
            const float p = fmaf(d, scale, shift);
            aggAll = fmaxf(aggAll, p);
            voxA   = fmaxf(voxA, p * mk);
        }
        float voxB;
        if (nvalid == 0)          voxB = 0.0f;
        else if (nvalid < TPTS)   voxB = fmaxf(aggAll, 0.0f);
        else                      voxB = aggAll;

        // direct scatter (duplicates accumulate; out was zeroed by fill_out)
        const int4 c = ((const int4*)coord)[k];   // 64 lanes share k -> L1 broadcast
        const int loc = (((c.x * DD + c.y) * HH + c.z) * WW + c.w);
        float* o = out + (size_t)loc * CO;
        atomicAdd(o + v,      voxA);
        atomicAdd(o + 64 + v, voxB);
    }
}

extern "C" void kernel_launch(void* const* d_in, const int* in_sizes, int n_in,
                              void* d_out, int out_size, void* d_ws, size_t ws_size,
                              hipStream_t stream) {
    const float* feat = (const float*)d_in[0];
    const float* w1   = (const float*)d_in[1];
    const float* b1   = (const float*)d_in[2];
    const float* g1   = (const float*)d_in[3];
    const float* be1  = (const float*)d_in[4];
    const float* m1   = (const float*)d_in[5];
    const float* v1   = (const float*)d_in[6];
    const float* w2   = (const float*)d_in[7];
    const float* b2   = (const float*)d_in[8];
    const float* g2   = (const float*)d_in[9];
    const float* be2  = (const float*)d_in[10];
    const float* m2   = (const float*)d_in[11];
    const float* v2   = (const float*)d_in[12];
    const int*   coord = (const int*)d_in[13];
    float* out = (float*)d_out;

    // No workspace dependence: zero-fill exactly the output, then compute +
    // scatter directly with atomics. Same-stream ordering guarantees the
    // fill completes before any atomicAdd lands.
    fill_out<<<FILLB, 256, 0, stream>>>((float4*)out);
    vfe_scatter<<<CB, 256, 0, stream>>>(feat, w1, b1, g1, be1, m1, v1,
                                        w2, b2, g2, be2, m2, v2, coord, out);
}